// Round 4
// baseline (205.167 us; speedup 1.0000x reference)
//
#include <hip/hip_runtime.h>
#include <math.h>

#define SIM_T 100

// ---------------------------------------------------------------------------
// Transpose encW [out][in] -> encWT [in][out] so GEMM weight reads are k-major.
// ---------------------------------------------------------------------------
__global__ __launch_bounds__(256) void k_transpose256(
    const float* __restrict__ W, float* __restrict__ WT) {
  int k = blockIdx.x;
  int o = threadIdx.x;
  WT[k * 256 + o] = W[o * 256 + k];
}

// ---------------------------------------------------------------------------
// Permute W2 [256][256] -> W2p so each lane's 4 columns are one contiguous
// float4:  W2p[i*256 + l*4 + q] = W2[i*256 + 64*q + l]
// ---------------------------------------------------------------------------
__global__ __launch_bounds__(256) void k_perm(const float* __restrict__ W2,
                                              float* __restrict__ W2p) {
  int i = blockIdx.x;
  int t = threadIdx.x;
  int l = t >> 2, q = t & 3;
  W2p[i * 256 + t] = W2[i * 256 + q * 64 + l];
}

// ---------------------------------------------------------------------------
// GEMM: O[row][col] = epi( sum_k A[row][k] * WT[k][col] )
// R4 structure ("RS"): lane = row, wave = 8-col slice. A row segment lives in
// REGISTERS (4 phases x 16 float4); W reads are wave-uniform -> pure s_load
// stream (only lgkmcnt user -> deep SMEM pipelining; R3's flaw was ds_read +
// s_load sharing lgkmcnt). Inner loop is fma-only, 8 fma per 32B W chunk.
// Per-lane A loads: 16B @ 1KB stride; consecutive unrolled loads reuse the
// same 64B line (L1 hit) so HBM traffic stays ~8MB. fmaf chain k-ascending
// per output == R1/R3 exact order (absmax 0 preserved).
// Grid: 1024 = 128 row-tiles x 8 col-groups; 4 blocks/CU, 4 waves/SIMD, 0 LDS.
// EPI 0: sigmoid(acc + bias)   EPI 1: acc * omd
// ---------------------------------------------------------------------------
template <int EPI>
__global__ __launch_bounds__(256, 4) void k_gemm_rs(
    const float* __restrict__ A,     // [8192][256]
    const float* __restrict__ WT,    // [256 k][256 col]
    const float* __restrict__ bias,  // encB (EPI=0) or unused
    float* __restrict__ O,           // [8192][256]
    float omd) {
  const int t = threadIdx.x;
  const int lane = t & 63;
  const int w = t >> 6;
  const int rt = blockIdx.x >> 3;  // 64-row tile
  const int cg = blockIdx.x & 7;   // 32-col group
  const int row = rt * 64 + lane;
  const int colbase_v = cg * 32 + w * 8;  // wave-uniform value
  const int colbase = __builtin_amdgcn_readfirstlane(colbase_v);
  const float4* arow4 = (const float4*)(A + (size_t)row * 256);
  const float* wp = WT + colbase;  // SGPR pointer

  float acc[8];
#pragma unroll
  for (int c = 0; c < 8; c++) acc[c] = 0.f;

#pragma unroll
  for (int ph = 0; ph < 4; ph++) {
    float4 a[16];
#pragma unroll
    for (int i = 0; i < 16; i++) a[i] = arow4[ph * 16 + i];
#pragma unroll
    for (int i = 0; i < 16; i++) {
      const float* af = &a[i].x;
#pragma unroll
      for (int kk = 0; kk < 4; kk++) {
        const int k = ph * 64 + i * 4 + kk;
        const float* wk = wp + k * 256;  // uniform -> s_load, imm offset
#pragma unroll
        for (int c = 0; c < 8; c++) acc[c] = fmaf(af[kk], wk[c], acc[c]);
      }
    }
  }

  float* obase = O + (size_t)row * 256 + colbase_v;
  if (EPI == 0) {
    float4 r0, r1;
    float* rf0 = &r0.x;
    float* rf1 = &r1.x;
#pragma unroll
    for (int c = 0; c < 4; c++) {
      float v = acc[c] + bias[colbase + c];
      rf0[c] = 1.f / (1.f + expf(-v));
      float v2 = acc[c + 4] + bias[colbase + c + 4];
      rf1[c] = 1.f / (1.f + expf(-v2));
    }
    *(float4*)obase = r0;
    *(float4*)(obase + 4) = r1;
  } else {
    float4 r0, r1;
    float* rf0 = &r0.x;
    float* rf1 = &r1.x;
#pragma unroll
    for (int c = 0; c < 4; c++) {
      rf0[c] = __fmul_rn(acc[c], omd);
      rf1[c] = __fmul_rn(acc[c + 4], omd);
    }
    *(float4*)obase = r0;
    *(float4*)(obase + 4) = r1;
  }
}

// ---------------------------------------------------------------------------
// Kernel: the 100-step LIF simulation. One wave == one batch row.
// Lane l owns columns {l, 64+l, 128+l, 192+l} of layers 1/2 and column l of
// layer 3. Spike sets via __ballot -> uniform scalar ctz loops; per spike one
// coalesced float4 load of the permuted W2 row.  (unchanged from R3: 75us,
// VALUBusy 79%, VALU-bound at its structural floor for this algorithm)
// ---------------------------------------------------------------------------
__global__ __launch_bounds__(256, 8) void k_sim(
    const float* __restrict__ c_in, const float* __restrict__ W2p,
    const float* __restrict__ W3, float* __restrict__ out, float decay,
    float omd) {
  const int lane = threadIdx.x & 63;
  const int row = blockIdx.x * 4 + (threadIdx.x >> 6);
  const float* crow = c_in + (long)row * 256;
  const float c0 = crow[lane];
  const float c1 = crow[64 + lane];
  const float c2 = crow[128 + lane];
  const float c3 = crow[192 + lane];
  float v10 = 0.f, v11 = 0.f, v12 = 0.f, v13 = 0.f;
  float v20 = 0.f, v21 = 0.f, v22 = 0.f, v23 = 0.f;
  float v3 = 0.f;
  int acc = 0;
  const float4* w2p = (const float4*)W2p + lane;  // w2p[i*64] = row i, 4 cols

  for (int t = 0; t < SIM_T; t++) {
    // ---- layer 1 (constant input c) ----
    v10 = __fadd_rn(__fmul_rn(v10, decay), c0);
    bool f0 = v10 >= 1.f;
    unsigned long long m0 = __ballot(f0);
    v10 = f0 ? 0.f : v10;
    v11 = __fadd_rn(__fmul_rn(v11, decay), c1);
    bool f1 = v11 >= 1.f;
    unsigned long long m1 = __ballot(f1);
    v11 = f1 ? 0.f : v11;
    v12 = __fadd_rn(__fmul_rn(v12, decay), c2);
    bool f2 = v12 >= 1.f;
    unsigned long long m2 = __ballot(f2);
    v12 = f2 ? 0.f : v12;
    v13 = __fadd_rn(__fmul_rn(v13, decay), c3);
    bool f3 = v13 >= 1.f;
    unsigned long long m3 = __ballot(f3);
    v13 = f3 ? 0.f : v13;

    // ---- layer 2: syn2 = sum of W2 rows of spiking layer-1 neurons ----
    float s0 = 0.f, s1 = 0.f, s2 = 0.f, s3 = 0.f;
#define ACC2(mask, qb)                            \
  {                                               \
    unsigned long long m = (mask);                \
    while (m) {                                   \
      int i = __builtin_ctzll(m) + (qb);          \
      m &= m - 1;                                 \
      float4 w = w2p[i * 64];                     \
      s0 += w.x;                                  \
      s1 += w.y;                                  \
      s2 += w.z;                                  \
      s3 += w.w;                                  \
    }                                             \
  }
    ACC2(m0, 0)
    ACC2(m1, 64)
    ACC2(m2, 128)
    ACC2(m3, 192)

    v20 = __fadd_rn(__fmul_rn(v20, decay), __fmul_rn(s0, omd));
    bool g0 = v20 >= 1.f;
    unsigned long long n0 = __ballot(g0);
    v20 = g0 ? 0.f : v20;
    v21 = __fadd_rn(__fmul_rn(v21, decay), __fmul_rn(s1, omd));
    bool g1 = v21 >= 1.f;
    unsigned long long n1 = __ballot(g1);
    v21 = g1 ? 0.f : v21;
    v22 = __fadd_rn(__fmul_rn(v22, decay), __fmul_rn(s2, omd));
    bool g2 = v22 >= 1.f;
    unsigned long long n2 = __ballot(g2);
    v22 = g2 ? 0.f : v22;
    v23 = __fadd_rn(__fmul_rn(v23, decay), __fmul_rn(s3, omd));
    bool g3 = v23 >= 1.f;
    unsigned long long n3 = __ballot(g3);
    v23 = g3 ? 0.f : v23;

    // ---- layer 3 (usually no layer-2 spikes: uniform skip) ----
    float z = 0.f;
    if (n0 | n1 | n2 | n3) {
#define ACC3(mask, qb)                            \
  {                                               \
    unsigned long long m = (mask);                \
    while (m) {                                   \
      int i = __builtin_ctzll(m) + (qb);          \
      m &= m - 1;                                 \
      z += W3[i * 64 + lane];                     \
    }                                             \
  }
      ACC3(n0, 0)
      ACC3(n1, 64)
      ACC3(n2, 128)
      ACC3(n3, 192)
    }
    v3 = __fadd_rn(__fmul_rn(v3, decay), __fmul_rn(z, omd));
    bool h = v3 >= 1.f;
    acc += h ? 1 : 0;
    v3 = h ? 0.f : v3;
  }
  out[(long)row * 64 + lane] = __fdiv_rn((float)acc, 100.f);
}

// ---------------------------------------------------------------------------
extern "C" void kernel_launch(void* const* d_in, const int* in_sizes, int n_in,
                              void* d_out, int out_size, void* d_ws,
                              size_t ws_size, hipStream_t stream) {
  const float* x = (const float*)d_in[0];     // [8192,256]
  const float* encW = (const float*)d_in[1];  // [256,256] (out,in)
  const float* encB = (const float*)d_in[2];  // [256]
  const float* W1 = (const float*)d_in[3];    // [256,256] (in,out) k-major
  const float* W2 = (const float*)d_in[4];    // [256,256]
  const float* W3 = (const float*)d_in[5];    // [256,64]
  float* out = (float*)d_out;                 // [8192,64]

  float* c = (float*)d_ws;                        // 8 MB
  float* rates = (float*)d_ws + 2097152;          // 8 MB
  float* W2p = (float*)d_ws + 4194304;            // 256 KB
  float* encWT = (float*)d_ws + 4194304 + 65536;  // 256 KB

  const float decay = (float)exp((double)(-0.05f));
  const float omd = 1.0f - decay;

  k_transpose256<<<256, 256, 0, stream>>>(encW, encWT);
  k_perm<<<256, 256, 0, stream>>>(W2, W2p);
  k_gemm_rs<0><<<1024, 256, 0, stream>>>(x, encWT, encB, rates, omd);
  k_gemm_rs<1><<<1024, 256, 0, stream>>>(rates, W1, encB, c, omd);
  k_sim<<<2048, 256, 0, stream>>>(c, W2p, W3, out, decay, omd);
}

// Round 5
// 181.299 us; speedup vs baseline: 1.1317x; 1.1317x over previous
//
#include <hip/hip_runtime.h>
#include <math.h>

#define SIM_T 100

// ---------------------------------------------------------------------------
// Transpose encW [out][in] -> encWT [in][out] so GEMM weight reads are k-major.
// 256KB total, L2-absorbed; ~few us.
// ---------------------------------------------------------------------------
__global__ __launch_bounds__(256) void k_transpose256(
    const float* __restrict__ W, float* __restrict__ WT) {
  int k = blockIdx.x;
  int o = threadIdx.x;
  WT[k * 256 + o] = W[o * 256 + k];
}

// ---------------------------------------------------------------------------
// Permute W2 [256][256] -> W2p so each lane's 4 columns are one contiguous
// float4:  W2p[i*256 + l*4 + q] = W2[i*256 + 64*q + l]
// ---------------------------------------------------------------------------
__global__ __launch_bounds__(256) void k_perm(const float* __restrict__ W2,
                                              float* __restrict__ W2p) {
  int i = blockIdx.x;
  int t = threadIdx.x;
  int l = t >> 2, q = t & 3;
  W2p[i * 256 + t] = W2[i * 256 + q * 64 + l];
}

// ---------------------------------------------------------------------------
// GEMM: O[row][col] = epi( sum_k A[row][k] * WT[k][col] )
// R5 structure ("lane = col-quad"): lane l owns output cols 4l..4l+3, so the
// W stream WT[k][4l..4l+3] is a coalesced float4/lane (1KB/instr), staged in
// LDS 32-k chunks (32KB) shared by 4 waves. A[row][k] is wave-uniform ->
// LDS broadcast ds_read_b128 (conflict-free). Inner loop: 8 ds_read_b128 +
// 64 fmaf per 4-k group; zero scalar loads, zero strided vector loads (the
// R3/R4 failure mode: W via 1KB-stride s_load, A uncoalesced 16B/lane).
// Block: 4 waves x 4 rows = 16 rows; grid 512; LDS 48KB -> 2 blocks/CU.
// fmaf chain k-ascending per output == R1..R4 exact order (absmax 0).
// EPI 0: sigmoid(acc + bias)   EPI 1: acc * omd
// ---------------------------------------------------------------------------
template <int EPI>
__global__ __launch_bounds__(256, 3) void k_gemm_lds(
    const float* __restrict__ A,     // [8192][256]
    const float* __restrict__ WT,    // [256 k][256 col]
    const float* __restrict__ bias,  // encB (EPI=0) or unused
    float* __restrict__ O,           // [8192][256]
    float omd) {
  __shared__ float4 lds_a[16 * 64];  // 16 rows x 256 floats = 16KB
  __shared__ float4 lds_w[32 * 64];  // 32 k x 256 floats = 32KB
  const int t = threadIdx.x;
  const int lane = t & 63;
  const int w = t >> 6;
  const int rowbase = blockIdx.x * 16;

  const float4* Ag = (const float4*)(A + (size_t)rowbase * 256);
  const float4* Wg = (const float4*)WT;

  // stage A tile (16KB, coalesced) + W chunk 0 (32KB, coalesced)
#pragma unroll
  for (int i = 0; i < 4; i++) lds_a[i * 256 + t] = Ag[i * 256 + t];
#pragma unroll
  for (int i = 0; i < 8; i++) lds_w[i * 256 + t] = Wg[i * 256 + t];
  __syncthreads();

  float4 acc[4];
#pragma unroll
  for (int r = 0; r < 4; r++) acc[r] = make_float4(0.f, 0.f, 0.f, 0.f);

  for (int kc = 0; kc < 8; kc++) {
    // compute chunk kc: k = kc*32 .. kc*32+31
#pragma unroll
    for (int kg = 0; kg < 8; kg++) {
      float4 w0 = lds_w[(kg * 4 + 0) * 64 + lane];
      float4 w1 = lds_w[(kg * 4 + 1) * 64 + lane];
      float4 w2 = lds_w[(kg * 4 + 2) * 64 + lane];
      float4 w3 = lds_w[(kg * 4 + 3) * 64 + lane];
#pragma unroll
      for (int r = 0; r < 4; r++) {
        float4 a = lds_a[(w * 4 + r) * 64 + (kc * 8 + kg)];  // broadcast
        // k ascending: kg*4+0, +1, +2, +3
        acc[r].x = fmaf(a.x, w0.x, acc[r].x);
        acc[r].y = fmaf(a.x, w0.y, acc[r].y);
        acc[r].z = fmaf(a.x, w0.z, acc[r].z);
        acc[r].w = fmaf(a.x, w0.w, acc[r].w);
        acc[r].x = fmaf(a.y, w1.x, acc[r].x);
        acc[r].y = fmaf(a.y, w1.y, acc[r].y);
        acc[r].z = fmaf(a.y, w1.z, acc[r].z);
        acc[r].w = fmaf(a.y, w1.w, acc[r].w);
        acc[r].x = fmaf(a.z, w2.x, acc[r].x);
        acc[r].y = fmaf(a.z, w2.y, acc[r].y);
        acc[r].z = fmaf(a.z, w2.z, acc[r].z);
        acc[r].w = fmaf(a.z, w2.w, acc[r].w);
        acc[r].x = fmaf(a.w, w3.x, acc[r].x);
        acc[r].y = fmaf(a.w, w3.y, acc[r].y);
        acc[r].z = fmaf(a.w, w3.z, acc[r].z);
        acc[r].w = fmaf(a.w, w3.w, acc[r].w);
      }
    }
    if (kc < 7) {
      __syncthreads();
#pragma unroll
      for (int i = 0; i < 8; i++)
        lds_w[i * 256 + t] = Wg[(kc + 1) * 2048 + i * 256 + t];
      __syncthreads();
    }
  }

  // epilogue: lane stores cols 4*lane..4*lane+3 of its wave's 4 rows
  float4* O4 = (float4*)O;
  if (EPI == 0) {
    float4 b = ((const float4*)bias)[lane];
#pragma unroll
    for (int r = 0; r < 4; r++) {
      int row = rowbase + w * 4 + r;
      float4 o;
      o.x = 1.f / (1.f + expf(-(acc[r].x + b.x)));
      o.y = 1.f / (1.f + expf(-(acc[r].y + b.y)));
      o.z = 1.f / (1.f + expf(-(acc[r].z + b.z)));
      o.w = 1.f / (1.f + expf(-(acc[r].w + b.w)));
      O4[(size_t)row * 64 + lane] = o;
    }
  } else {
#pragma unroll
    for (int r = 0; r < 4; r++) {
      int row = rowbase + w * 4 + r;
      float4 o;
      o.x = __fmul_rn(acc[r].x, omd);
      o.y = __fmul_rn(acc[r].y, omd);
      o.z = __fmul_rn(acc[r].z, omd);
      o.w = __fmul_rn(acc[r].w, omd);
      O4[(size_t)row * 64 + lane] = o;
    }
  }
}

// ---------------------------------------------------------------------------
// Kernel: the 100-step LIF simulation. One wave == one batch row.
// Lane l owns columns {l, 64+l, 128+l, 192+l} of layers 1/2 and column l of
// layer 3. Spike sets via __ballot -> uniform scalar ctz loops; per spike one
// coalesced float4 load of the permuted W2 row.  (unchanged: 75us, VALUBusy
// 79%, VALU-bound at its structural floor for this algorithm)
// ---------------------------------------------------------------------------
__global__ __launch_bounds__(256, 8) void k_sim(
    const float* __restrict__ c_in, const float* __restrict__ W2p,
    const float* __restrict__ W3, float* __restrict__ out, float decay,
    float omd) {
  const int lane = threadIdx.x & 63;
  const int row = blockIdx.x * 4 + (threadIdx.x >> 6);
  const float* crow = c_in + (long)row * 256;
  const float c0 = crow[lane];
  const float c1 = crow[64 + lane];
  const float c2 = crow[128 + lane];
  const float c3 = crow[192 + lane];
  float v10 = 0.f, v11 = 0.f, v12 = 0.f, v13 = 0.f;
  float v20 = 0.f, v21 = 0.f, v22 = 0.f, v23 = 0.f;
  float v3 = 0.f;
  int acc = 0;
  const float4* w2p = (const float4*)W2p + lane;  // w2p[i*64] = row i, 4 cols

  for (int t = 0; t < SIM_T; t++) {
    // ---- layer 1 (constant input c) ----
    v10 = __fadd_rn(__fmul_rn(v10, decay), c0);
    bool f0 = v10 >= 1.f;
    unsigned long long m0 = __ballot(f0);
    v10 = f0 ? 0.f : v10;
    v11 = __fadd_rn(__fmul_rn(v11, decay), c1);
    bool f1 = v11 >= 1.f;
    unsigned long long m1 = __ballot(f1);
    v11 = f1 ? 0.f : v11;
    v12 = __fadd_rn(__fmul_rn(v12, decay), c2);
    bool f2 = v12 >= 1.f;
    unsigned long long m2 = __ballot(f2);
    v12 = f2 ? 0.f : v12;
    v13 = __fadd_rn(__fmul_rn(v13, decay), c3);
    bool f3 = v13 >= 1.f;
    unsigned long long m3 = __ballot(f3);
    v13 = f3 ? 0.f : v13;

    // ---- layer 2: syn2 = sum of W2 rows of spiking layer-1 neurons ----
    float s0 = 0.f, s1 = 0.f, s2 = 0.f, s3 = 0.f;
#define ACC2(mask, qb)                            \
  {                                               \
    unsigned long long m = (mask);                \
    while (m) {                                   \
      int i = __builtin_ctzll(m) + (qb);          \
      m &= m - 1;                                 \
      float4 w = w2p[i * 64];                     \
      s0 += w.x;                                  \
      s1 += w.y;                                  \
      s2 += w.z;                                  \
      s3 += w.w;                                  \
    }                                             \
  }
    ACC2(m0, 0)
    ACC2(m1, 64)
    ACC2(m2, 128)
    ACC2(m3, 192)

    v20 = __fadd_rn(__fmul_rn(v20, decay), __fmul_rn(s0, omd));
    bool g0 = v20 >= 1.f;
    unsigned long long n0 = __ballot(g0);
    v20 = g0 ? 0.f : v20;
    v21 = __fadd_rn(__fmul_rn(v21, decay), __fmul_rn(s1, omd));
    bool g1 = v21 >= 1.f;
    unsigned long long n1 = __ballot(g1);
    v21 = g1 ? 0.f : v21;
    v22 = __fadd_rn(__fmul_rn(v22, decay), __fmul_rn(s2, omd));
    bool g2 = v22 >= 1.f;
    unsigned long long n2 = __ballot(g2);
    v22 = g2 ? 0.f : v22;
    v23 = __fadd_rn(__fmul_rn(v23, decay), __fmul_rn(s3, omd));
    bool g3 = v23 >= 1.f;
    unsigned long long n3 = __ballot(g3);
    v23 = g3 ? 0.f : v23;

    // ---- layer 3 (usually no layer-2 spikes: uniform skip) ----
    float z = 0.f;
    if (n0 | n1 | n2 | n3) {
#define ACC3(mask, qb)                            \
  {                                               \
    unsigned long long m = (mask);                \
    while (m) {                                   \
      int i = __builtin_ctzll(m) + (qb);          \
      m &= m - 1;                                 \
      z += W3[i * 64 + lane];                     \
    }                                             \
  }
      ACC3(n0, 0)
      ACC3(n1, 64)
      ACC3(n2, 128)
      ACC3(n3, 192)
    }
    v3 = __fadd_rn(__fmul_rn(v3, decay), __fmul_rn(z, omd));
    bool h = v3 >= 1.f;
    acc += h ? 1 : 0;
    v3 = h ? 0.f : v3;
  }
  out[(long)row * 64 + lane] = __fdiv_rn((float)acc, 100.f);
}

// ---------------------------------------------------------------------------
extern "C" void kernel_launch(void* const* d_in, const int* in_sizes, int n_in,
                              void* d_out, int out_size, void* d_ws,
                              size_t ws_size, hipStream_t stream) {
  const float* x = (const float*)d_in[0];     // [8192,256]
  const float* encW = (const float*)d_in[1];  // [256,256] (out,in)
  const float* encB = (const float*)d_in[2];  // [256]
  const float* W1 = (const float*)d_in[3];    // [256,256] (in,out) k-major
  const float* W2 = (const float*)d_in[4];    // [256,256]
  const float* W3 = (const float*)d_in[5];    // [256,64]
  float* out = (float*)d_out;                 // [8192,64]

  float* c = (float*)d_ws;                        // 8 MB
  float* rates = (float*)d_ws + 2097152;          // 8 MB
  float* W2p = (float*)d_ws + 4194304;            // 256 KB
  float* encWT = (float*)d_ws + 4194304 + 65536;  // 256 KB

  const float decay = (float)exp((double)(-0.05f));
  const float omd = 1.0f - decay;

  k_transpose256<<<256, 256, 0, stream>>>(encW, encWT);
  k_perm<<<256, 256, 0, stream>>>(W2, W2p);
  k_gemm_lds<0><<<512, 256, 0, stream>>>(x, encWT, encB, rates, omd);
  k_gemm_lds<1><<<512, 256, 0, stream>>>(rates, W1, encB, c, omd);
  k_sim<<<2048, 256, 0, stream>>>(c, W2p, W3, out, decay, omd);
}